// Round 10
// baseline (595.353 us; speedup 1.0000x reference)
//
#include <hip/hip_runtime.h>

// Sinkhorn divergence, 512 independent 256-point problems, 24 annealing steps.
// Round 12: half-column-per-lane-group. NT=1024, 2 blocks/CU = 8 waves/SIMD
// (2x R9's 4 — R9's 36% occupancy + 2.6x gap over the VALU-pipe floor said
// latency-hiding, not issue count, is the limiter). Wave layout: waves 0-7 =
// pair A {xy->f, yy->py} over ya; waves 8-15 = pair B {yx->g, xx->px} over
// xa. Within a wave: lanes 0-31 = rows w*32..w*32+31 cols 0-127, lanes
// 32-63 = SAME rows, cols 128-255. Half-merge is register-only (2 shfl_xor
// + exact integer-ldexp merge, canonical lo/hi order -> both halves get
// bit-identical pots). Keeps R9's 0.5 b128/elem amortization, 1 barrier/
// step, double-buffered H. 2-address wave reads = free 2-way (m136).
// NO ext_vector types (R3/R4: scratch demotion).
//
// Math (log2 domain, element path identical to R9): online logsumexp,
// integer-quantized running max (ceilf), ldexp rescale — exact identity.
//   arg_ij = H[j] + (ti*inv)*t_j + (coef_i*inv)*z_j
//   H[j]   = la2 + (pot_prev[j] - self[j])*inv ,  inv = log2e/eps

constexpr int   N       = 256;   // points per cloud
constexpr int   NPROB   = 512;   // B*S*NR
constexpr int   NRDIM   = 64;
constexpr float DT_F    = 0.001f;
constexpr float EPS_MIN = 1e-4f; // BLUR^P
constexpr int   NSTEPS  = 24;
constexpr float LOG2E   = 1.4426950408889634f;
constexpr float LN2     = 0.6931471805599453f;
constexpr int   NT      = 1024;  // threads per block (16 waves)

extern "C" __global__ void __launch_bounds__(NT, 8)
sinkhorn_div_kernel(const float* __restrict__ syn,
                    const float* __restrict__ obs,
                    float* __restrict__ divs)
{
    const int p    = blockIdx.x;         // ((b*S + s)*NR + r)
    const int r    = p & (NRDIM - 1);
    const int bs   = p >> 6;
    const int tid  = threadIdx.x;
    const int lane = tid & 63;
    const int wave = tid >> 6;           // 0..15
    const int pair = tid >> 9;           // 0: A={xy,yy} over ya ; 1: B={yx,xx} over xa
    const int half = lane >> 5;          // 0: cols 0-127 ; 1: cols 128-255
    const int row  = ((wave & 7) << 5) | (lane & 31);   // 0..255

    __shared__ float4 ya4[2][N];         // [buf][col] = (Hxy, Hyy, y_j, t_j)
    __shared__ float4 xa4[2][N];         // [buf][col] = (Hyx, Hxx, x_j, t_j)
    __shared__ float  redA[64];

    float* yaF = (float*)ya4;            // word view: buf*1024 + j*4 + w
    float* xaF = (float*)xa4;

    const size_t base = (size_t)bs * N * NRDIM + r;
    const float xi = obs[base + (size_t)row * NRDIM];   // x cloud = obs
    const float yi = syn[base + (size_t)row * NRDIM];   // y cloud = syn
    const float ti = (float)row * DT_F;

    // ---- one-time init: static column coords into BOTH buffers ----
    if (half == 0) {
        if (pair == 0) {
            const float2 w2 = make_float2(yi, ti);
            *(float2*)&yaF[       row * 4 + 2] = w2;
            *(float2*)&yaF[1024 + row * 4 + 2] = w2;
        } else {
            const float2 w2 = make_float2(xi, ti);
            *(float2*)&xaF[       row * 4 + 2] = w2;
            *(float2*)&xaF[1024 + row * 4 + 2] = w2;
        }
    }

    // ---- block reductions: diameter (max/min) + all-zero mask sums ----
    // (rows duplicated across halves/pairs: fine for max/min & zero-tests)
    float hi = fmaxf(xi, yi), lo = fminf(xi, yi);
    float ax = fabsf(xi),     ay = fabsf(yi);
    #pragma unroll
    for (int off = 32; off > 0; off >>= 1) {
        hi  = fmaxf(hi, __shfl_down(hi, off, 64));
        lo  = fminf(lo, __shfl_down(lo, off, 64));
        ax += __shfl_down(ax, off, 64);
        ay += __shfl_down(ay, off, 64);
    }
    if ((tid & 63) == 0) {
        redA[wave * 4 + 0] = hi;  redA[wave * 4 + 1] = lo;
        redA[wave * 4 + 2] = ax;  redA[wave * 4 + 3] = ay;
    }
    __syncthreads();                     // also covers coord init writes
    float vmax = -3.4e38f, vmin = 3.4e38f, sax = 0.0f, say = 0.0f;
    #pragma unroll
    for (int w = 0; w < 16; ++w) {
        vmax = fmaxf(vmax, redA[w * 4 + 0]);
        vmin = fminf(vmin, redA[w * 4 + 1]);
        sax += redA[w * 4 + 2];
        say += redA[w * 4 + 3];
    }

    const float tspread  = 255.0f * DT_F;
    const float diameter = fmaxf(tspread, vmax - vmin);
    float eps_raw = diameter * diameter;              // eps0 = diameter^2

    const float selfx = 0.5f * (ti * ti + xi * xi);
    const float selfy = 0.5f * (ti * ti + yi * yi);
    const float la2   = -8.0f;                        // log2(1/256)

    // pair A: pot1=f (selfx, xi), pot2=py (selfy, yi)
    // pair B: pot1=g (selfy, yi), pot2=px (selfx, xi)
    const float self1 = (pair == 0) ? selfx : selfy;
    const float self2 = (pair == 0) ? selfy : selfx;
    const float cf1   = (pair == 0) ? xi : yi;
    const float cf2   = (pair == 0) ? yi : xi;

    float pot1 = 0.0f, pot2 = 0.0f;

    const int jhalf = half << 7;         // my column range start

#define EXP2(x) __builtin_amdgcn_exp2f(x)

    for (int step = 0; step < NSTEPS; ++step) {
        const float eps = fmaxf(eps_raw, EPS_MIN);
        const float inv = LOG2E / eps;
        const int   bo  = (step & 1) * 1024;     // word offset of H buffer

        // ---- prologue: half 0 cross-feeds potentials as next H columns ----
        if (half == 0) {
            const float h1 = fmaf(pot1 - self1, inv, la2);
            const float h2 = fmaf(pot2 - self2, inv, la2);
            if (pair == 0) {      // f -> Hyx (xa.x) ; py -> Hyy (ya.y)
                xaF[bo + row * 4 + 0] = h1;
                yaF[bo + row * 4 + 1] = h2;
            } else {              // g -> Hxy (ya.x) ; px -> Hxx (xa.y)
                yaF[bo + row * 4 + 0] = h1;
                xaF[bo + row * 4 + 1] = h2;
            }
        }
        __syncthreads();          // the ONLY barrier this step

        const float tii = ti * inv;
        const float c1  = cf1 * inv;
        const float c2  = cf2 * inv;
        const float4* __restrict__ Hq = (pair == 0) ? &ya4[step & 1][0]
                                                    : &xa4[step & 1][0];

        float m0 = -1e9f, m1 = -1e9f, s0 = 0.0f, s1 = 0.0f;
        #pragma unroll 4
        for (int cc = 0; cc < 128; cc += 8) {
            const int jb = jhalf + cc;
            const float4 Q0 = Hq[jb + 0];
            const float4 Q1 = Hq[jb + 1];
            const float4 Q2 = Hq[jb + 2];
            const float4 Q3 = Hq[jb + 3];
            const float4 Q4 = Hq[jb + 4];
            const float4 Q5 = Hq[jb + 5];
            const float4 Q6 = Hq[jb + 6];
            const float4 Q7 = Hq[jb + 7];
            const float b0 = fmaf(c1, Q0.z, fmaf(tii, Q0.w, Q0.x));
            const float c0_ = fmaf(c2, Q0.z, fmaf(tii, Q0.w, Q0.y));
            const float b1 = fmaf(c1, Q1.z, fmaf(tii, Q1.w, Q1.x));
            const float c1_ = fmaf(c2, Q1.z, fmaf(tii, Q1.w, Q1.y));
            const float b2 = fmaf(c1, Q2.z, fmaf(tii, Q2.w, Q2.x));
            const float c2_ = fmaf(c2, Q2.z, fmaf(tii, Q2.w, Q2.y));
            const float b3 = fmaf(c1, Q3.z, fmaf(tii, Q3.w, Q3.x));
            const float c3_ = fmaf(c2, Q3.z, fmaf(tii, Q3.w, Q3.y));
            const float b4 = fmaf(c1, Q4.z, fmaf(tii, Q4.w, Q4.x));
            const float c4_ = fmaf(c2, Q4.z, fmaf(tii, Q4.w, Q4.y));
            const float b5 = fmaf(c1, Q5.z, fmaf(tii, Q5.w, Q5.x));
            const float c5_ = fmaf(c2, Q5.z, fmaf(tii, Q5.w, Q5.y));
            const float b6 = fmaf(c1, Q6.z, fmaf(tii, Q6.w, Q6.x));
            const float c6_ = fmaf(c2, Q6.z, fmaf(tii, Q6.w, Q6.y));
            const float b7 = fmaf(c1, Q7.z, fmaf(tii, Q7.w, Q7.x));
            const float c7_ = fmaf(c2, Q7.z, fmaf(tii, Q7.w, Q7.y));
            // 9-leaf max trees; m0/m1 integer-valued (or -1e9), ceil-safe
            const float bt0 = fmaxf(fmaxf(b0, b1), b2);
            const float bt1 = fmaxf(fmaxf(b3, b4), b5);
            const float bt2 = fmaxf(fmaxf(b6, b7), m0);
            const float M0  = ceilf(fmaxf(fmaxf(bt0, bt1), bt2));
            const float ct0 = fmaxf(fmaxf(c0_, c1_), c2_);
            const float ct1 = fmaxf(fmaxf(c3_, c4_), c5_);
            const float ct2 = fmaxf(fmaxf(c6_, c7_), m1);
            const float M1  = ceilf(fmaxf(fmaxf(ct0, ct1), ct2));
            const float t0 =
                ((EXP2(b0 - M0) + EXP2(b1 - M0)) + (EXP2(b2 - M0) + EXP2(b3 - M0))) +
                ((EXP2(b4 - M0) + EXP2(b5 - M0)) + (EXP2(b6 - M0) + EXP2(b7 - M0)));
            const float t1 =
                ((EXP2(c0_ - M1) + EXP2(c1_ - M1)) + (EXP2(c2_ - M1) + EXP2(c3_ - M1))) +
                ((EXP2(c4_ - M1) + EXP2(c5_ - M1)) + (EXP2(c6_ - M1) + EXP2(c7_ - M1)));
            s0 = ldexpf(s0, (int)(m0 - M0)) + t0;  m0 = M0;   // integer delta
            s1 = ldexpf(s1, (int)(m1 - M1)) + t1;  m1 = M1;
        }

        // ---- register-only half-merge (canonical lo/hi order: both halves
        //      compute bit-identical results; m's integer-valued -> exact) --
        {
            const float mo0 = __shfl_xor(m0, 32, 64);
            const float so0 = __shfl_xor(s0, 32, 64);
            const float ml  = (half == 0) ? m0 : mo0;
            const float sl  = (half == 0) ? s0 : so0;
            const float mh  = (half == 0) ? mo0 : m0;
            const float sh  = (half == 0) ? so0 : s0;
            m0 = fmaxf(ml, mh);
            s0 = ldexpf(sl, (int)(ml - m0)) + ldexpf(sh, (int)(mh - m0));
        }
        {
            const float mo1 = __shfl_xor(m1, 32, 64);
            const float so1 = __shfl_xor(s1, 32, 64);
            const float ml  = (half == 0) ? m1 : mo1;
            const float sl  = (half == 0) ? s1 : so1;
            const float mh  = (half == 0) ? mo1 : m1;
            const float sh  = (half == 0) ? so1 : s1;
            m1 = fmaxf(ml, mh);
            s1 = ldexpf(sl, (int)(ml - m1)) + ldexpf(sh, (int)(mh - m1));
        }

        // ---- epilogue: thread-local softmin finish (2 logs) ----
        const float el2 = eps * LN2;
        pot1 = self1 - el2 * (m0 + __builtin_amdgcn_logf(s0));                  // f / g
        pot2 = 0.5f * (pot2 + (self2 - el2 * (m1 + __builtin_amdgcn_logf(s1)))); // py / px

        eps_raw *= 0.25f;
        // next prologue writes buf^1; step t's reads of buf are separated
        // from step t+2's writes of buf by step t+1's barrier.
    }
#undef EXP2

    // ---- divergence: half 0 holds (f - py) [pair A] / (g - px) [pair B] ----
    float contrib = (half == 0) ? (pot1 - pot2) : 0.0f;
    #pragma unroll
    for (int off = 32; off > 0; off >>= 1)
        contrib += __shfl_down(contrib, off, 64);
    __syncthreads();                      // redA reuse
    if ((tid & 63) == 0) redA[wave] = contrib;
    __syncthreads();
    if (tid == 0) {
        float total = 0.0f;
        #pragma unroll
        for (int w = 0; w < 16; ++w) total += redA[w];
        total *= (1.0f / (float)N);
        const bool masked_out = (sax == 0.0f) && (say == 0.0f);
        divs[p] = masked_out ? 0.0f : total;
    }
}

extern "C" __global__ void __launch_bounds__(256)
reduce_out_kernel(const float* __restrict__ divs, float* __restrict__ out)
{
    const int b   = blockIdx.x;
    const int tid = threadIdx.x;
    __shared__ float red[4];
    float v = divs[b * 256 + tid];        // 256 = S*NR problems per batch
    #pragma unroll
    for (int off = 32; off > 0; off >>= 1)
        v += __shfl_down(v, off, 64);
    if ((tid & 63) == 0) red[tid >> 6] = v;
    __syncthreads();
    if (tid == 0) out[b] = red[0] + red[1] + red[2] + red[3];
}

extern "C" void kernel_launch(void* const* d_in, const int* in_sizes, int n_in,
                              void* d_out, int out_size, void* d_ws, size_t ws_size,
                              hipStream_t stream) {
    const float* syn = (const float*)d_in[0];   // syn_data
    const float* obs = (const float*)d_in[1];   // obs_data
    float* divs = (float*)d_ws;                 // 512 floats scratch

    sinkhorn_div_kernel<<<NPROB, NT, 0, stream>>>(syn, obs, divs);
    reduce_out_kernel<<<2, 256, 0, stream>>>(divs, (float*)d_out);
}

// Round 13
// 546.506 us; speedup vs baseline: 1.0894x; 1.0894x over previous
//
#include <hip/hip_runtime.h>

// Sinkhorn divergence, 512 independent 256-point problems, 24 annealing steps.
// Round 15: R9 skeleton (589us best) + column-PAIR packed layout, pure-C
// v2f math (__builtin_elementwise_fma / native v2f add-sub). R12's NaN was
// a sizing bug: 2 cols/group needs N/2=128 groups, not N/4 (prologue wrote
// past the buffer). Fixed: yaH[2][128], wslot<=509 < 512 words/buffer,
// k-loop sweeps all 128 groups. No inline asm, no op_sel (R11's NaN):
// semantics guaranteed; LLVM selects v_pk_fma_f32/v_pk_add_f32 for v2f on
// CDNA. Scratch-demotion risk removed by the 128-VGPR cap
// (launch_bounds(512,4)) — R3/R4 spilled under the 64-cap.
// LDS (12 KB):
//   yaH[2][128] quad {Hxy_2k, Hxy_2k+1, Hyy_2k, Hyy_2k+1}  (per buf)
//   xaH[2][128] quad {Hyx_2k, Hyx_2k+1, Hxx_2k, Hxx_2k+1}
//   yaW[128]    quad {y_2k, y_2k+1, t_2k, t_2k+1}   (static)
//   xaW[128]    quad {x_2k, x_2k+1, t_2k, t_2k+1}
// Packed multiplicands are loop-invariant: {tii,tii},{c1,c1},{c2,c2}.
// Math: online logsumexp, integer-quantized running max (ceilf), ldexp
// rescale — exact; packed sum tree reassociates (threshold 5.48).

constexpr int   N       = 256;   // points per cloud
constexpr int   NPROB   = 512;   // B*S*NR
constexpr int   NRDIM   = 64;
constexpr float DT_F    = 0.001f;
constexpr float EPS_MIN = 1e-4f; // BLUR^P
constexpr int   NSTEPS  = 24;
constexpr float LOG2E   = 1.4426950408889634f;
constexpr float LN2     = 0.6931471805599453f;
constexpr int   NT      = 512;   // threads per block (8 waves)
constexpr int   NG      = N / 2; // 128 column-pair groups

typedef float v2f __attribute__((ext_vector_type(2)));

extern "C" __global__ void __launch_bounds__(NT, 4)
sinkhorn_div_kernel(const float* __restrict__ syn,
                    const float* __restrict__ obs,
                    float* __restrict__ divs)
{
    const int p    = blockIdx.x;         // ((b*S + s)*NR + r)
    const int r    = p & (NRDIM - 1);
    const int bs   = p >> 6;
    const int tid  = threadIdx.x;
    const int row  = tid & (N - 1);      // row index i
    const int pair = tid >> 8;           // 0: A={xy,yy} over y-side ; 1: B={yx,xx} over x-side

    __shared__ float4 yaH[2][NG];        // y-side H per buf (4 KB)
    __shared__ float4 xaH[2][NG];        // x-side H per buf (4 KB)
    __shared__ float4 yaW[NG];           // y-side coords (2 KB, static)
    __shared__ float4 xaW[NG];           // x-side coords (2 KB, static)
    __shared__ float  redA[32];

    float* yaHF = (float*)yaH;           // word views: buf*512 + wslot
    float* xaHF = (float*)xaH;
    float* yaWF = (float*)yaW;
    float* xaWF = (float*)xaW;

    const size_t base = (size_t)bs * N * NRDIM + r;
    const float xi = obs[base + (size_t)row * NRDIM];   // x cloud = obs
    const float yi = syn[base + (size_t)row * NRDIM];   // y cloud = syn
    const float ti = (float)row * DT_F;

    // word slot of column `row`: group g=row>>1, H1/z at g*4+(row&1), H2/t at +2
    const int wslot = ((row >> 1) << 2) | (row & 1);    // 0..509

    // ---- one-time init: static column coords ----
    if (pair == 0) {
        yaWF[wslot]     = yi;
        yaWF[wslot + 2] = ti;
    } else {
        xaWF[wslot]     = xi;
        xaWF[wslot + 2] = ti;
    }

    // ---- block reductions: diameter (max/min) + all-zero mask sums ----
    float hi = fmaxf(xi, yi), lo = fminf(xi, yi);
    float ax = fabsf(xi),     ay = fabsf(yi);
    #pragma unroll
    for (int off = 32; off > 0; off >>= 1) {
        hi  = fmaxf(hi, __shfl_down(hi, off, 64));
        lo  = fminf(lo, __shfl_down(lo, off, 64));
        ax += __shfl_down(ax, off, 64);
        ay += __shfl_down(ay, off, 64);
    }
    const int wave = tid >> 6;           // 0..7
    if ((tid & 63) == 0) {
        redA[wave * 4 + 0] = hi;  redA[wave * 4 + 1] = lo;
        redA[wave * 4 + 2] = ax;  redA[wave * 4 + 3] = ay;
    }
    __syncthreads();                     // also covers coord init writes
    float vmax = -3.4e38f, vmin = 3.4e38f, sax = 0.0f, say = 0.0f;
    #pragma unroll
    for (int w = 0; w < 8; ++w) {
        vmax = fmaxf(vmax, redA[w * 4 + 0]);
        vmin = fminf(vmin, redA[w * 4 + 1]);
        sax += redA[w * 4 + 2];
        say += redA[w * 4 + 3];
    }

    const float tspread  = 255.0f * DT_F;
    const float diameter = fmaxf(tspread, vmax - vmin);
    float eps_raw = diameter * diameter;              // eps0 = diameter^2

    const float selfx = 0.5f * (ti * ti + xi * xi);
    const float selfy = 0.5f * (ti * ti + yi * yi);
    const float la2   = -8.0f;                        // log2(1/256)

    // pair A: pot1=f (selfx, xi) reads y-side; pot2=py (selfy, yi)
    // pair B: pot1=g (selfy, yi) reads x-side; pot2=px (selfx, xi)
    const float self1 = (pair == 0) ? selfx : selfy;
    const float self2 = (pair == 0) ? selfy : selfx;
    const float cf1   = (pair == 0) ? xi : yi;
    const float cf2   = (pair == 0) ? yi : xi;

    float pot1 = 0.0f, pot2 = 0.0f;

#define EXP2(x) __builtin_amdgcn_exp2f(x)

// One 2-column group: Q = H quad, W = coord quad -> packed args AB (stream1),
// AC (stream2). Multiplicand pairs are loop-invariant; pure-C v2f fma.
#define GRP(Q, W, AB, AC) do { \
        const v2f hb_ = {Q.x, Q.y}; const v2f hc_ = {Q.z, Q.w}; \
        const v2f zz_ = {W.x, W.y}; const v2f tt_ = {W.z, W.w}; \
        AB = __builtin_elementwise_fma(zz_, c1v, \
                 __builtin_elementwise_fma(tt_, tii2, hb_)); \
        AC = __builtin_elementwise_fma(zz_, c2v, \
                 __builtin_elementwise_fma(tt_, tii2, hc_)); \
    } while (0)

    for (int step = 0; step < NSTEPS; ++step) {
        const float eps = fmaxf(eps_raw, EPS_MIN);
        const float inv = LOG2E / eps;
        const int   buf = step & 1;
        const int   bo  = buf * (NG * 4);        // word offset of H buffer

        // ---- prologue: cross-feed my potentials as next H columns ----
        const float h1 = fmaf(pot1 - self1, inv, la2);
        const float h2 = fmaf(pot2 - self2, inv, la2);
        if (pair == 0) {          // f -> Hyx (x-side H1) ; py -> Hyy (y-side H2)
            xaHF[bo + wslot]     = h1;
            yaHF[bo + wslot + 2] = h2;
        } else {                  // g -> Hxy (y-side H1) ; px -> Hxx (x-side H2)
            yaHF[bo + wslot]     = h1;
            xaHF[bo + wslot + 2] = h2;
        }
        __syncthreads();          // the ONLY barrier this step

        const float tii = ti * inv;
        const v2f tii2 = {tii, tii};
        const v2f c1v  = {cf1 * inv, cf1 * inv};
        const v2f c2v  = {cf2 * inv, cf2 * inv};
        const float4* __restrict__ Hq = (pair == 0) ? &yaH[buf][0] : &xaH[buf][0];
        const float4* __restrict__ Wq = (pair == 0) ? &yaW[0]      : &xaW[0];

        float m0 = -1e9f, m1 = -1e9f, s0 = 0.0f, s1 = 0.0f;
        #pragma unroll 2
        for (int k = 0; k < NG; k += 4) {        // 4 groups = 8 columns
            const float4 Q0 = Hq[k + 0];
            const float4 Q1 = Hq[k + 1];
            const float4 Q2 = Hq[k + 2];
            const float4 Q3 = Hq[k + 3];
            const float4 W0 = Wq[k + 0];
            const float4 W1 = Wq[k + 1];
            const float4 W2 = Wq[k + 2];
            const float4 W3 = Wq[k + 3];
            v2f ab0, ab1, ab2, ab3, ac0, ac1, ac2, ac3;
            GRP(Q0, W0, ab0, ac0);
            GRP(Q1, W1, ab1, ac1);
            GRP(Q2, W2, ab2, ac2);
            GRP(Q3, W3, ab3, ac3);
            // scalar max trees on pair halves; m0/m1 integer-valued
            // (or -1e9) -> folding before ceil stays exact
            const float bt0 = fmaxf(fmaxf(ab0.x, ab0.y), ab1.x);
            const float bt1 = fmaxf(fmaxf(ab1.y, ab2.x), ab2.y);
            const float bt2 = fmaxf(fmaxf(ab3.x, ab3.y), m0);
            const float M0  = ceilf(fmaxf(fmaxf(bt0, bt1), bt2));
            const float ct0 = fmaxf(fmaxf(ac0.x, ac0.y), ac1.x);
            const float ct1 = fmaxf(fmaxf(ac1.y, ac2.x), ac2.y);
            const float ct2 = fmaxf(fmaxf(ac3.x, ac3.y), m1);
            const float M1  = ceilf(fmaxf(fmaxf(ct0, ct1), ct2));
            const v2f M0v = {M0, M0};
            const v2f M1v = {M1, M1};
            const v2f ub0 = ab0 - M0v, ub1 = ab1 - M0v;
            const v2f ub2 = ab2 - M0v, ub3 = ab3 - M0v;
            const v2f uc0 = ac0 - M1v, uc1 = ac1 - M1v;
            const v2f uc2 = ac2 - M1v, uc3 = ac3 - M1v;
            v2f eb0, eb1, eb2, eb3, ec0, ec1, ec2, ec3;
            eb0.x = EXP2(ub0.x); eb0.y = EXP2(ub0.y);
            eb1.x = EXP2(ub1.x); eb1.y = EXP2(ub1.y);
            eb2.x = EXP2(ub2.x); eb2.y = EXP2(ub2.y);
            eb3.x = EXP2(ub3.x); eb3.y = EXP2(ub3.y);
            ec0.x = EXP2(uc0.x); ec0.y = EXP2(uc0.y);
            ec1.x = EXP2(uc1.x); ec1.y = EXP2(uc1.y);
            ec2.x = EXP2(uc2.x); ec2.y = EXP2(uc2.y);
            ec3.x = EXP2(uc3.x); ec3.y = EXP2(uc3.y);
            const v2f pb0 = eb0 + eb1, pb1 = eb2 + eb3;
            const v2f qb  = pb0 + pb1;
            const v2f pc0 = ec0 + ec1, pc1 = ec2 + ec3;
            const v2f qc  = pc0 + pc1;
            s0 = ldexpf(s0, (int)(m0 - M0)) + (qb.x + qb.y);  m0 = M0;
            s1 = ldexpf(s1, (int)(m1 - M1)) + (qc.x + qc.y);  m1 = M1;
        }

        // ---- epilogue: thread-local softmin finish (2 logs) ----
        const float el2 = eps * LN2;
        pot1 = self1 - el2 * (m0 + __builtin_amdgcn_logf(s0));                  // f / g
        pot2 = 0.5f * (pot2 + (self2 - el2 * (m1 + __builtin_amdgcn_logf(s1)))); // py / px

        eps_raw *= 0.25f;
        // next prologue writes buf^1; step t's reads of buf are separated
        // from step t+2's writes of buf by step t+1's barrier.
    }
#undef GRP
#undef EXP2

    // ---- divergence: pair A holds (f - py), pair B holds (g - px) ----
    float contrib = pot1 - pot2;
    #pragma unroll
    for (int off = 32; off > 0; off >>= 1)
        contrib += __shfl_down(contrib, off, 64);
    __syncthreads();                      // redA reuse
    if ((tid & 63) == 0) redA[wave] = contrib;
    __syncthreads();
    if (tid == 0) {
        float total = 0.0f;
        #pragma unroll
        for (int w = 0; w < 8; ++w) total += redA[w];
        total *= (1.0f / (float)N);
        const bool masked_out = (sax == 0.0f) && (say == 0.0f);
        divs[p] = masked_out ? 0.0f : total;
    }
}

extern "C" __global__ void __launch_bounds__(256)
reduce_out_kernel(const float* __restrict__ divs, float* __restrict__ out)
{
    const int b   = blockIdx.x;
    const int tid = threadIdx.x;
    __shared__ float red[4];
    float v = divs[b * 256 + tid];        // 256 = S*NR problems per batch
    #pragma unroll
    for (int off = 32; off > 0; off >>= 1)
        v += __shfl_down(v, off, 64);
    if ((tid & 63) == 0) red[tid >> 6] = v;
    __syncthreads();
    if (tid == 0) out[b] = red[0] + red[1] + red[2] + red[3];
}

extern "C" void kernel_launch(void* const* d_in, const int* in_sizes, int n_in,
                              void* d_out, int out_size, void* d_ws, size_t ws_size,
                              hipStream_t stream) {
    const float* syn = (const float*)d_in[0];   // syn_data
    const float* obs = (const float*)d_in[1];   // obs_data
    float* divs = (float*)d_ws;                 // 512 floats scratch

    sinkhorn_div_kernel<<<NPROB, NT, 0, stream>>>(syn, obs, divs);
    reduce_out_kernel<<<2, 256, 0, stream>>>(divs, (float*)d_out);
}